// Round 13
// baseline (126.649 us; speedup 1.0000x reference)
//
#include <hip/hip_runtime.h>
#include <stdint.h>

typedef __attribute__((ext_vector_type(8))) short bf16x8;
typedef __attribute__((ext_vector_type(4))) float f32x4;
typedef __attribute__((ext_vector_type(16))) float f32x16;

__device__ __forceinline__ unsigned short f32_to_bf16(float f) {
  union { float f; uint32_t u; } v; v.f = f;
  uint32_t u = v.u;
  u += 0x7fffu + ((u >> 16) & 1u);
  return (unsigned short)(u >> 16);
}

__device__ __forceinline__ float bf16_to_f32(unsigned short s) {
  union { uint32_t u; float f; } v; v.u = ((uint32_t)s) << 16;
  return v.f;
}

__device__ __forceinline__ uint32_t cvt_pk_bf16(float a, float b) {
  uint32_t r;
  asm("v_cvt_pk_bf16_f32 %0, %1, %2" : "=v"(r) : "v"(a), "v"(b));
  return r;
}

__device__ __forceinline__ void async_copy16(void* lds, const void* g) {
  __builtin_amdgcn_global_load_lds(
      (const __attribute__((address_space(1))) unsigned int*)g,
      (__attribute__((address_space(3))) unsigned int*)lds, 16, 0, 0);
}

// ---------------------------------------------------------------------------
// Kernel A2: weight convert to bf16.
// ---------------------------------------------------------------------------
__global__ __launch_bounds__(256) void wcvt_kernel(
    const float* __restrict__ Wt, const float* __restrict__ Wp,
    const float* __restrict__ Wg, const float* __restrict__ Wz,
    unsigned short* __restrict__ Wcat, unsigned short* __restrict__ Wzb) {
  int e = (blockIdx.x * 256 + threadIdx.x) * 4;
  const float* src;
  unsigned short* dst;
  int off;
  if (e < 32768) { src = Wt; dst = Wcat; off = e; }
  else if (e < 65536) { src = Wp; dst = Wcat + 32768; off = e - 32768; }
  else if (e < 98304) { src = Wg; dst = Wcat + 65536; off = e - 65536; }
  else { src = Wz; dst = Wzb; off = e - 98304; }
  float4 v = *(const float4*)(src + off);
  union { uint2 u; unsigned short s[4]; } pk;
  pk.s[0] = f32_to_bf16(v.x); pk.s[1] = f32_to_bf16(v.y);
  pk.s[2] = f32_to_bf16(v.z); pk.s[3] = f32_to_bf16(v.w);
  *(uint2*)(dst + off) = pk.u;
}

// ---------------------------------------------------------------------------
// Kernel B: FUSED transpose + MFMA projections (r12-proven).
// Q,K: [b][n][128] bf16.  Vt: [b][128][n] bf16, n-bits 2,3 swapped.
// ---------------------------------------------------------------------------
__global__ __launch_bounds__(512, 2) void proj_kernel(
    const float* __restrict__ x,
    const unsigned short* __restrict__ Wcat,
    const float* __restrict__ bt, const float* __restrict__ bp,
    const float* __restrict__ bg,
    unsigned short* __restrict__ Q, unsigned short* __restrict__ Km,
    unsigned short* __restrict__ Vt) {
  __shared__ __align__(1024) unsigned short xs[128 * 256];
  __shared__ unsigned short tmp[32][132];  // padded: 2-way max on r/w
  const int t = threadIdx.x;
  const int lane = t & 63;
  const int w = t >> 6;
  const int nt = blockIdx.x;
  const int b = blockIdx.y;
  const int n0 = nt * 128;

  const float* xb = x + (size_t)b * 256 * 4096;
  unsigned char* lbase = (unsigned char*)xs;

  // stage: 8 chunks of 32 c x 128 n
  for (int cc = 0; cc < 8; ++cc) {
#pragma unroll
    for (int i = 0; i < 2; ++i) {
      int idx = i * 512 + t;            // 0..1023
      int c = idx >> 5;                 // 0..31
      int n4 = (idx & 31) * 4;          // 0..124
      float4 v = *(const float4*)(xb + (size_t)(cc * 32 + c) * 4096 + n0 + n4);
      union { uint2 u; unsigned short s[4]; } pk;
      pk.s[0] = f32_to_bf16(v.x); pk.s[1] = f32_to_bf16(v.y);
      pk.s[2] = f32_to_bf16(v.z); pk.s[3] = f32_to_bf16(v.w);
      *(uint2*)&tmp[c][n4] = pk.u;
    }
    __syncthreads();
    {
      int n = t >> 2;                   // 0..127
      int ch = t & 3;                   // 0..3 (8-c group)
      union { uint4 u; unsigned short s[8]; } pk;
#pragma unroll
      for (int jj = 0; jj < 8; ++jj) pk.s[jj] = tmp[ch * 8 + jj][n];
      int byt = n * 512 + ((cc * 64 + ch * 16) ^ ((n & 7) << 4));
      *(uint4*)(lbase + byt) = pk.u;
    }
    __syncthreads();
  }

  const int rl = lane & 15, gh = lane >> 4;
  const int swz = (rl & 7) << 4;
  const int rlv = (rl & 3) | ((rl & 4) << 1) | ((rl & 8) >> 1);  // bit2<->bit3

  f32x4 aQ[8], aK[8], aV[8];
#pragma unroll
  for (int i = 0; i < 8; ++i) {
    aQ[i] = (f32x4){0.f, 0.f, 0.f, 0.f};
    aK[i] = (f32x4){0.f, 0.f, 0.f, 0.f};
    aV[i] = (f32x4){0.f, 0.f, 0.f, 0.f};
  }

  const unsigned char* wq =
      (const unsigned char*)Wcat + ((w * 16 + rl) * 256) * 2 + gh * 16;
  const unsigned char* wk = wq + 128 * 512;
  const unsigned char* wv = wq + 256 * 512;

#pragma unroll
  for (int kk = 0; kk < 8; ++kk) {
    bf16x8 xf[8];
#pragma unroll
    for (int n2 = 0; n2 < 8; ++n2)
      xf[n2] = *(const bf16x8*)(lbase + (n2 * 16 + rl) * 512 +
                                ((kk * 64 + gh * 16) ^ swz));
    bf16x8 fq = *(const bf16x8*)(wq + kk * 64);
    bf16x8 fk = *(const bf16x8*)(wk + kk * 64);
    bf16x8 fv = *(const bf16x8*)(wv + kk * 64);
#pragma unroll
    for (int n2 = 0; n2 < 8; ++n2) {
      aQ[n2] = __builtin_amdgcn_mfma_f32_16x16x32_bf16(xf[n2], fq, aQ[n2], 0, 0, 0);
      aK[n2] = __builtin_amdgcn_mfma_f32_16x16x32_bf16(xf[n2], fk, aK[n2], 0, 0, 0);
      aV[n2] = __builtin_amdgcn_mfma_f32_16x16x32_bf16(fv, xf[n2], aV[n2], 0, 0, 0);
    }
  }

  const float btv = bt[w * 16 + rl];
  const float bpv = bp[w * 16 + rl];
  float bgv[4];
#pragma unroll
  for (int j = 0; j < 4; ++j) bgv[j] = bg[w * 16 + gh * 4 + j];

  unsigned short* Qb = Q + ((size_t)b * 4096 + n0) * 128 + w * 16 + rl;
  unsigned short* Kb = Km + ((size_t)b * 4096 + n0) * 128 + w * 16 + rl;
  unsigned short* Vb = Vt + (size_t)b * 128 * 4096 + n0 + rlv;
#pragma unroll
  for (int n2 = 0; n2 < 8; ++n2) {
#pragma unroll
    for (int j = 0; j < 4; ++j) {
      int n = n2 * 16 + gh * 4 + j;
      Qb[(size_t)n * 128] = f32_to_bf16(aQ[n2][j] + btv);
      Kb[(size_t)n * 128] = f32_to_bf16(aK[n2][j] + bpv);
      int o = w * 16 + gh * 4 + j;
      Vb[(size_t)o * 4096 + n2 * 16] = f32_to_bf16(aV[n2][j] + bgv[j]);
    }
  }
}

// ---------------------------------------------------------------------------
// Kernel C: flash attention.  Identical structure/resources to the proven
// r6 kernel.  CHANGE: per-q online max (m lives per lane, q = lane&31;
// partner exchange = ONE shfl_xor(32)) instead of the 6-shfl wave-uniform
// chain.  Rescale correctness: acc row r belongs to q=crow(r,hi); its
// factor is broadcast with __shfl(sc, crow) (partners hold identical sc).
// Epilogue already stores per-q (m,l); fused combine handles per-q m.
// ---------------------------------------------------------------------------
__global__ __launch_bounds__(256, 2) void attn_kernel(
    const unsigned short* __restrict__ Qg,
    const unsigned short* __restrict__ Kg,
    const unsigned short* __restrict__ Vg,
    unsigned short* __restrict__ Opart,
    float* __restrict__ Marr, float* __restrict__ Larr) {
  __shared__ __align__(1024) unsigned char smem[65536];
  const int t = threadIdx.x;
  const int lane = t & 63;
  const int w = t >> 6;
  const int q31 = lane & 31;
  const int hi = lane >> 5;
  const int kswz = (q31 & 15) << 4;

  const int orig = blockIdx.x;
  const int b = orig & 7;  // XCD-pinned batch
  const int idx = orig >> 3;
  const int h = idx & 1;
  const int qg = idx >> 1;
  const int qw = qg * 128 + w * 32;
  const int kv0 = h * 2048;

  const unsigned short* Qb = Qg + (size_t)b * 4096 * 128;
  const unsigned short* Kb = Kg + (size_t)b * 4096 * 128;
  const unsigned short* Vb = Vg + (size_t)b * 128 * 4096;

  bf16x8 qf[8];
  {
    const unsigned char* qp =
        (const unsigned char*)(Qb + (size_t)(qw + q31) * 128) + hi * 16;
#pragma unroll
    for (int dc = 0; dc < 8; ++dc) qf[dc] = *(const bf16x8*)(qp + dc * 32);
  }

  // staging addresses (LDS dest linear per seg; global source pre-swizzled)
  const unsigned char* ksrc[4];
  const unsigned char* vsrc[4];
  unsigned int kofs[4], vofs[4];
#pragma unroll
  for (int ii = 0; ii < 4; ++ii) {
    int seg = w * 4 + ii;
    {
      int r = seg * 4 + (lane >> 4);
      int kcol = ((lane & 15) * 16) ^ ((r & 15) << 4);
      ksrc[ii] = (const unsigned char*)(Kb + (size_t)(kv0 + r) * 128) + kcol;
      kofs[ii] = seg * 1024;
    }
    {
      int o = seg * 1024 + lane * 16;      // linear LDS offset in V region
      int R = o >> 8;
      int cp = (o & 255) ^ ((R & 15) << 4);
      int d = 2 * R + (cp >> 7);
      int kvb = cp & 127;
      vsrc[ii] = (const unsigned char*)(Vb + (size_t)d * 4096 + kv0) + kvb;
      vofs[ii] = 16384 + seg * 1024;
    }
  }

  f32x16 acc[4];
#pragma unroll
  for (int i = 0; i < 4; ++i)
#pragma unroll
    for (int e = 0; e < 16; ++e) acc[i][e] = 0.f;
  float m = -1e30f, l = 0.f;

#pragma unroll
  for (int ii = 0; ii < 4; ++ii) {
    async_copy16(smem + kofs[ii], ksrc[ii]);
    async_copy16(smem + vofs[ii], vsrc[ii]);
  }
  __syncthreads();

#pragma unroll 2
  for (int it = 0; it < 32; ++it) {
    unsigned char* bb = smem + (it & 1) * 32768;
    if (it + 1 < 32) {
      unsigned int nb = ((it + 1) & 1) * 32768;
      size_t ko = (size_t)(it + 1) * 16384;
      int vo2 = (it + 1) * 128;
#pragma unroll
      for (int ii = 0; ii < 4; ++ii) {
        async_copy16(smem + nb + kofs[ii], ksrc[ii] + ko);
        async_copy16(smem + nb + vofs[ii], vsrc[ii] + vo2);
      }
    }

    // S^T = K·Q^T : two 32-kv tiles, 8 d-steps each
    f32x16 st0, st1;
#pragma unroll
    for (int e = 0; e < 16; ++e) { st0[e] = 0.f; st1[e] = 0.f; }
    const unsigned char* kb0 = bb + q31 * 256;
    const unsigned char* kb1 = bb + (32 + q31) * 256;
    __builtin_amdgcn_s_setprio(1);
#pragma unroll
    for (int dc = 0; dc < 8; ++dc) {
      int off = (dc * 32 + hi * 16) ^ kswz;
      bf16x8 k0 = *(const bf16x8*)(kb0 + off);
      bf16x8 k1 = *(const bf16x8*)(kb1 + off);
      st0 = __builtin_amdgcn_mfma_f32_32x32x16_bf16(k0, qf[dc], st0, 0, 0, 0);
      st1 = __builtin_amdgcn_mfma_f32_32x32x16_bf16(k1, qf[dc], st1, 0, 0, 0);
    }
    __builtin_amdgcn_s_setprio(0);

    // per-q online max: tree over own 32 regs, ONE partner shfl
    float t8[8];
#pragma unroll
    for (int e = 0; e < 8; ++e)
      t8[e] = fmaxf(fmaxf(st0[e], st0[e + 8]), fmaxf(st1[e], st1[e + 8]));
#pragma unroll
    for (int e = 0; e < 4; ++e) t8[e] = fmaxf(t8[e], t8[e + 4]);
    float tmax = fmaxf(fmaxf(t8[0], t8[1]), fmaxf(t8[2], t8[3]));
    tmax = fmaxf(tmax, __shfl_xor(tmax, 32));   // pair-max = per-q max
    if (__any(tmax > m + 8.f)) {  // defer-max: uniform branch, per-q sc
      float mn = fmaxf(m, tmax);
      float sc = __expf(m - mn);
      m = mn;
      l *= sc;
#pragma unroll
      for (int r = 0; r < 16; ++r) {
        int crow = (r & 3) + 8 * (r >> 2) + 4 * hi;  // q-row of acc reg r
        float scr = __shfl(sc, crow);  // partners hold identical sc
        acc[0][r] *= scr; acc[1][r] *= scr;
        acc[2][r] *= scr; acc[3][r] *= scr;
      }
    }
    float ls = 0.f;
#pragma unroll
    for (int e = 0; e < 16; ++e) { st0[e] = __expf(st0[e] - m); ls += st0[e]; }
#pragma unroll
    for (int e = 0; e < 16; ++e) { st1[e] = __expf(st1[e] - m); ls += st1[e]; }
    l += ls;

    // O += P·V : P A-frag in-register (V kv-columns pre-permuted in proj)
    const unsigned char* vbase = bb + 16384 + (q31 >> 1) * 256;
    const int vhb = (q31 & 1) << 7;
    const int vswz = (q31 >> 1) << 4;
#pragma unroll
    for (int ks = 0; ks < 4; ++ks) {
      union { uint32_t u[4]; bf16x8 v; } pk;
      if (ks == 0) {
        pk.u[0] = cvt_pk_bf16(st0[0], st0[1]);
        pk.u[1] = cvt_pk_bf16(st0[2], st0[3]);
        pk.u[2] = cvt_pk_bf16(st0[4], st0[5]);
        pk.u[3] = cvt_pk_bf16(st0[6], st0[7]);
      } else if (ks == 1) {
        pk.u[0] = cvt_pk_bf16(st0[8], st0[9]);
        pk.u[1] = cvt_pk_bf16(st0[10], st0[11]);
        pk.u[2] = cvt_pk_bf16(st0[12], st0[13]);
        pk.u[3] = cvt_pk_bf16(st0[14], st0[15]);
      } else if (ks == 2) {
        pk.u[0] = cvt_pk_bf16(st1[0], st1[1]);
        pk.u[1] = cvt_pk_bf16(st1[2], st1[3]);
        pk.u[2] = cvt_pk_bf16(st1[4], st1[5]);
        pk.u[3] = cvt_pk_bf16(st1[6], st1[7]);
      } else {
        pk.u[0] = cvt_pk_bf16(st1[8], st1[9]);
        pk.u[1] = cvt_pk_bf16(st1[10], st1[11]);
        pk.u[2] = cvt_pk_bf16(st1[12], st1[13]);
        pk.u[3] = cvt_pk_bf16(st1[14], st1[15]);
      }
      __builtin_amdgcn_s_setprio(1);
#pragma unroll
      for (int dt = 0; dt < 4; ++dt) {
        bf16x8 vf = *(const bf16x8*)(
            vbase + dt * 4096 + ((vhb | (ks * 32 + hi * 16)) ^ vswz));
        acc[dt] = __builtin_amdgcn_mfma_f32_32x32x16_bf16(pk.v, vf, acc[dt], 0, 0, 0);
      }
      __builtin_amdgcn_s_setprio(0);
    }
    __syncthreads();
  }

  // epilogue: store partial O (unnormalized bf16) + per-q m, l
  float lf = l + __shfl_xor(l, 32);
  if (lane < 32) {
    size_t ix = (size_t)h * 32768 + (size_t)b * 4096 + qw + q31;
    Marr[ix] = m;
    Larr[ix] = lf;
  }
  unsigned short* ob = Opart + (size_t)h * 32768 * 128;
#pragma unroll
  for (int dt = 0; dt < 4; ++dt)
#pragma unroll
    for (int r = 0; r < 16; ++r) {
      int qrow = qw + (r & 3) + 8 * (r >> 2) + 4 * hi;
      ob[((size_t)b * 4096 + qrow) * 128 + dt * 32 + q31] =
          f32_to_bf16(acc[dt][r]);
    }
}

// ---------------------------------------------------------------------------
// Kernel D: FUSED combine + z = Wz.y + bz + BN + residual (f32 x).
// ---------------------------------------------------------------------------
__global__ __launch_bounds__(512, 2) void outz_kernel(
    const unsigned short* __restrict__ Opart,
    const float* __restrict__ Marr, const float* __restrict__ Larr,
    const unsigned short* __restrict__ Wzb,
    const float* __restrict__ x, const float* __restrict__ bz,
    const float* __restrict__ gamma, const float* __restrict__ beta,
    const float* __restrict__ rmean, const float* __restrict__ rvar,
    float* __restrict__ out) {
  __shared__ __align__(1024) unsigned short ys[128 * 128];
  const int t = threadIdx.x;
  const int lane = t & 63;
  const int w = t >> 6;
  const int nt = blockIdx.x;
  const int b = blockIdx.y;
  const int n0 = nt * 128;

  unsigned char* lbase = (unsigned char*)ys;
#pragma unroll
  for (int i = 0; i < 4; ++i) {
    int off = (w * 4 + i) * 1024 + lane * 16;
    int n = off >> 8;                       // local q row 0..127
    int cb = (off & 255) ^ ((n & 7) << 4);  // byte col in Y row (16-aligned)
    size_t qidx = (size_t)b * 4096 + n0 + n;
    float m0 = Marr[qidx], m1 = Marr[32768 + qidx];
    float l0 = Larr[qidx], l1 = Larr[32768 + qidx];
    float M = fmaxf(m0, m1);
    float e0 = __expf(m0 - M), e1 = __expf(m1 - M);
    float rd = 1.f / (e0 * l0 + e1 * l1);
    float f0 = e0 * rd, f1 = e1 * rd;
    const unsigned char* ob = (const unsigned char*)Opart;
    const bf16x8 o0 = *(const bf16x8*)(ob + qidx * 256 + cb);
    const bf16x8 o1 = *(const bf16x8*)(ob + 32768ull * 256 + qidx * 256 + cb);
    union { uint4 u4; unsigned short s[8]; } pk;
#pragma unroll
    for (int e = 0; e < 8; ++e)
      pk.s[e] = f32_to_bf16(f0 * bf16_to_f32((unsigned short)o0[e]) +
                            f1 * bf16_to_f32((unsigned short)o1[e]));
    *(uint4*)(lbase + off) = pk.u4;
  }
  __syncthreads();

  const int rl = lane & 15, gh = lane >> 4;
  const int swz = (rl & 7) << 4;

  f32x4 acc[2][8];
#pragma unroll
  for (int i = 0; i < 2; ++i)
#pragma unroll
    for (int j = 0; j < 8; ++j) acc[i][j] = (f32x4){0.f, 0.f, 0.f, 0.f};

  const unsigned char* wz0 =
      (const unsigned char*)Wzb + ((w * 2) * 16 + rl) * 256 + gh * 16;

#pragma unroll
  for (int kk = 0; kk < 4; ++kk) {
    bf16x8 yf[8];
#pragma unroll
    for (int n2 = 0; n2 < 8; ++n2)
      yf[n2] = *(const bf16x8*)(lbase + (n2 * 16 + rl) * 256 +
                                ((kk * 64 + gh * 16) ^ swz));
    bf16x8 f0 = *(const bf16x8*)(wz0 + kk * 64);
    bf16x8 f1 = *(const bf16x8*)(wz0 + 16 * 256 + kk * 64);
#pragma unroll
    for (int n2 = 0; n2 < 8; ++n2) {
      acc[0][n2] = __builtin_amdgcn_mfma_f32_16x16x32_bf16(f0, yf[n2], acc[0][n2], 0, 0, 0);
      acc[1][n2] = __builtin_amdgcn_mfma_f32_16x16x32_bf16(f1, yf[n2], acc[1][n2], 0, 0, 0);
    }
  }

#pragma unroll
  for (int ot = 0; ot < 2; ++ot) {
#pragma unroll
    for (int j = 0; j < 4; ++j) {
      int o = (w * 2 + ot) * 16 + gh * 4 + j;
      float scale = gamma[o] * rsqrtf(rvar[o] + 1e-5f);
      float shift = (bz[o] - rmean[o]) * scale + beta[o];
      const float* xr = x + ((size_t)b * 256 + o) * 4096 + n0;
      float* orow = out + ((size_t)b * 256 + o) * 4096 + n0;
#pragma unroll
      for (int n2 = 0; n2 < 8; ++n2) {
        int n = n2 * 16 + rl;
        orow[n] = acc[ot][n2][j] * scale + shift + xr[n];
      }
    }
  }
}

// ---------------------------------------------------------------------------
extern "C" void kernel_launch(void* const* d_in, const int* in_sizes, int n_in,
                              void* d_out, int out_size, void* d_ws,
                              size_t ws_size, hipStream_t stream) {
  const float* x     = (const float*)d_in[0];
  const float* Wt    = (const float*)d_in[1];
  const float* bt    = (const float*)d_in[2];
  const float* Wp    = (const float*)d_in[3];
  const float* bp    = (const float*)d_in[4];
  const float* Wg    = (const float*)d_in[5];
  const float* bg    = (const float*)d_in[6];
  const float* Wz    = (const float*)d_in[7];
  const float* bz    = (const float*)d_in[8];
  const float* gamma = (const float*)d_in[9];
  const float* beta  = (const float*)d_in[10];
  const float* rmean = (const float*)d_in[11];
  const float* rvar  = (const float*)d_in[12];
  float* out = (float*)d_out;

  const size_t NE = (size_t)8 * 4096 * 128;  // 4,194,304
  unsigned short* Wcat  = (unsigned short*)d_ws;       // 98304 sh
  unsigned short* Wzb   = Wcat + 98304;                // 32768 sh
  float*          Marr  = (float*)(Wzb + 32768);       // 2*32768 f32
  float*          Larr  = Marr + 2 * 32768;            // 2*32768 f32
  unsigned short* Opart = (unsigned short*)(Larr + 2 * 32768);  // 2*NE sh
  unsigned short* Q     = Opart + 2 * NE;
  unsigned short* Km    = Q + NE;
  unsigned short* Vt    = Km + NE;

  wcvt_kernel<<<128, 256, 0, stream>>>(Wt, Wp, Wg, Wz, Wcat, Wzb);
  proj_kernel<<<dim3(32, 8), 512, 0, stream>>>(x, Wcat, bt, bp, bg, Q, Km, Vt);
  attn_kernel<<<512, 256, 0, stream>>>(Q, Km, Vt, Opart, Marr, Larr);
  outz_kernel<<<dim3(32, 8), 512, 0, stream>>>(Opart, Marr, Larr, Wzb, x, bz,
                                               gamma, beta, rmean, rvar, out);
}

// Round 14
// 123.872 us; speedup vs baseline: 1.0224x; 1.0224x over previous
//
#include <hip/hip_runtime.h>
#include <stdint.h>

typedef __attribute__((ext_vector_type(8))) short bf16x8;
typedef __attribute__((ext_vector_type(4))) float f32x4;
typedef __attribute__((ext_vector_type(16))) float f32x16;

__device__ __forceinline__ unsigned short f32_to_bf16(float f) {
  union { float f; uint32_t u; } v; v.f = f;
  uint32_t u = v.u;
  u += 0x7fffu + ((u >> 16) & 1u);
  return (unsigned short)(u >> 16);
}

__device__ __forceinline__ float bf16_to_f32(unsigned short s) {
  union { uint32_t u; float f; } v; v.u = ((uint32_t)s) << 16;
  return v.f;
}

__device__ __forceinline__ uint32_t cvt_pk_bf16(float a, float b) {
  uint32_t r;
  asm("v_cvt_pk_bf16_f32 %0, %1, %2" : "=v"(r) : "v"(a), "v"(b));
  return r;
}

__device__ __forceinline__ void async_copy16(void* lds, const void* g) {
  __builtin_amdgcn_global_load_lds(
      (const __attribute__((address_space(1))) unsigned int*)g,
      (__attribute__((address_space(3))) unsigned int*)lds, 16, 0, 0);
}

// ---------------------------------------------------------------------------
// Kernel A2: weight convert to bf16.
// ---------------------------------------------------------------------------
__global__ __launch_bounds__(256) void wcvt_kernel(
    const float* __restrict__ Wt, const float* __restrict__ Wp,
    const float* __restrict__ Wg, const float* __restrict__ Wz,
    unsigned short* __restrict__ Wcat, unsigned short* __restrict__ Wzb) {
  int e = (blockIdx.x * 256 + threadIdx.x) * 4;
  const float* src;
  unsigned short* dst;
  int off;
  if (e < 32768) { src = Wt; dst = Wcat; off = e; }
  else if (e < 65536) { src = Wp; dst = Wcat + 32768; off = e - 32768; }
  else if (e < 98304) { src = Wg; dst = Wcat + 65536; off = e - 65536; }
  else { src = Wz; dst = Wzb; off = e - 98304; }
  float4 v = *(const float4*)(src + off);
  union { uint2 u; unsigned short s[4]; } pk;
  pk.s[0] = f32_to_bf16(v.x); pk.s[1] = f32_to_bf16(v.y);
  pk.s[2] = f32_to_bf16(v.z); pk.s[3] = f32_to_bf16(v.w);
  *(uint2*)(dst + off) = pk.u;
}

// ---------------------------------------------------------------------------
// Kernel B: FUSED transpose + MFMA projections (r12-proven).
// Q,K: [b][n][128] bf16.  Vt: [b][128][n] bf16, n-bits 2,3 swapped.
// ---------------------------------------------------------------------------
__global__ __launch_bounds__(512, 2) void proj_kernel(
    const float* __restrict__ x,
    const unsigned short* __restrict__ Wcat,
    const float* __restrict__ bt, const float* __restrict__ bp,
    const float* __restrict__ bg,
    unsigned short* __restrict__ Q, unsigned short* __restrict__ Km,
    unsigned short* __restrict__ Vt) {
  __shared__ __align__(1024) unsigned short xs[128 * 256];
  __shared__ unsigned short tmp[32][132];  // padded: 2-way max on r/w
  const int t = threadIdx.x;
  const int lane = t & 63;
  const int w = t >> 6;
  const int nt = blockIdx.x;
  const int b = blockIdx.y;
  const int n0 = nt * 128;

  const float* xb = x + (size_t)b * 256 * 4096;
  unsigned char* lbase = (unsigned char*)xs;

  // stage: 8 chunks of 32 c x 128 n
  for (int cc = 0; cc < 8; ++cc) {
#pragma unroll
    for (int i = 0; i < 2; ++i) {
      int idx = i * 512 + t;            // 0..1023
      int c = idx >> 5;                 // 0..31
      int n4 = (idx & 31) * 4;          // 0..124
      float4 v = *(const float4*)(xb + (size_t)(cc * 32 + c) * 4096 + n0 + n4);
      union { uint2 u; unsigned short s[4]; } pk;
      pk.s[0] = f32_to_bf16(v.x); pk.s[1] = f32_to_bf16(v.y);
      pk.s[2] = f32_to_bf16(v.z); pk.s[3] = f32_to_bf16(v.w);
      *(uint2*)&tmp[c][n4] = pk.u;
    }
    __syncthreads();
    {
      int n = t >> 2;                   // 0..127
      int ch = t & 3;                   // 0..3 (8-c group)
      union { uint4 u; unsigned short s[8]; } pk;
#pragma unroll
      for (int jj = 0; jj < 8; ++jj) pk.s[jj] = tmp[ch * 8 + jj][n];
      int byt = n * 512 + ((cc * 64 + ch * 16) ^ ((n & 7) << 4));
      *(uint4*)(lbase + byt) = pk.u;
    }
    __syncthreads();
  }

  const int rl = lane & 15, gh = lane >> 4;
  const int swz = (rl & 7) << 4;
  const int rlv = (rl & 3) | ((rl & 4) << 1) | ((rl & 8) >> 1);  // bit2<->bit3

  f32x4 aQ[8], aK[8], aV[8];
#pragma unroll
  for (int i = 0; i < 8; ++i) {
    aQ[i] = (f32x4){0.f, 0.f, 0.f, 0.f};
    aK[i] = (f32x4){0.f, 0.f, 0.f, 0.f};
    aV[i] = (f32x4){0.f, 0.f, 0.f, 0.f};
  }

  const unsigned char* wq =
      (const unsigned char*)Wcat + ((w * 16 + rl) * 256) * 2 + gh * 16;
  const unsigned char* wk = wq + 128 * 512;
  const unsigned char* wv = wq + 256 * 512;

#pragma unroll
  for (int kk = 0; kk < 8; ++kk) {
    bf16x8 xf[8];
#pragma unroll
    for (int n2 = 0; n2 < 8; ++n2)
      xf[n2] = *(const bf16x8*)(lbase + (n2 * 16 + rl) * 512 +
                                ((kk * 64 + gh * 16) ^ swz));
    bf16x8 fq = *(const bf16x8*)(wq + kk * 64);
    bf16x8 fk = *(const bf16x8*)(wk + kk * 64);
    bf16x8 fv = *(const bf16x8*)(wv + kk * 64);
#pragma unroll
    for (int n2 = 0; n2 < 8; ++n2) {
      aQ[n2] = __builtin_amdgcn_mfma_f32_16x16x32_bf16(xf[n2], fq, aQ[n2], 0, 0, 0);
      aK[n2] = __builtin_amdgcn_mfma_f32_16x16x32_bf16(xf[n2], fk, aK[n2], 0, 0, 0);
      aV[n2] = __builtin_amdgcn_mfma_f32_16x16x32_bf16(fv, xf[n2], aV[n2], 0, 0, 0);
    }
  }

  const float btv = bt[w * 16 + rl];
  const float bpv = bp[w * 16 + rl];
  float bgv[4];
#pragma unroll
  for (int j = 0; j < 4; ++j) bgv[j] = bg[w * 16 + gh * 4 + j];

  unsigned short* Qb = Q + ((size_t)b * 4096 + n0) * 128 + w * 16 + rl;
  unsigned short* Kb = Km + ((size_t)b * 4096 + n0) * 128 + w * 16 + rl;
  unsigned short* Vb = Vt + (size_t)b * 128 * 4096 + n0 + rlv;
#pragma unroll
  for (int n2 = 0; n2 < 8; ++n2) {
#pragma unroll
    for (int j = 0; j < 4; ++j) {
      int n = n2 * 16 + gh * 4 + j;
      Qb[(size_t)n * 128] = f32_to_bf16(aQ[n2][j] + btv);
      Kb[(size_t)n * 128] = f32_to_bf16(aK[n2][j] + bpv);
      int o = w * 16 + gh * 4 + j;
      Vb[(size_t)o * 4096 + n2 * 16] = f32_to_bf16(aV[n2][j] + bgv[j]);
    }
  }
}

// ---------------------------------------------------------------------------
// Kernel C: flash attention — r6/r12 structure (proven).  One change:
// the wave-uniform max reduce (6-shfl chain) is GATED behind
// __any(lane_max > m+8), which is mathematically identical to
// (wave_max > m+8).  Common path: 31-op per-lane tree + 1 cmp, no shfls.
// ---------------------------------------------------------------------------
__global__ __launch_bounds__(256, 2) void attn_kernel(
    const unsigned short* __restrict__ Qg,
    const unsigned short* __restrict__ Kg,
    const unsigned short* __restrict__ Vg,
    unsigned short* __restrict__ Opart,
    float* __restrict__ Marr, float* __restrict__ Larr) {
  __shared__ __align__(1024) unsigned char smem[65536];
  const int t = threadIdx.x;
  const int lane = t & 63;
  const int w = t >> 6;
  const int q31 = lane & 31;
  const int hi = lane >> 5;
  const int kswz = (q31 & 15) << 4;

  const int orig = blockIdx.x;
  const int b = orig & 7;  // XCD-pinned batch
  const int idx = orig >> 3;
  const int h = idx & 1;
  const int qg = idx >> 1;
  const int qw = qg * 128 + w * 32;
  const int kv0 = h * 2048;

  const unsigned short* Qb = Qg + (size_t)b * 4096 * 128;
  const unsigned short* Kb = Kg + (size_t)b * 4096 * 128;
  const unsigned short* Vb = Vg + (size_t)b * 128 * 4096;

  bf16x8 qf[8];
  {
    const unsigned char* qp =
        (const unsigned char*)(Qb + (size_t)(qw + q31) * 128) + hi * 16;
#pragma unroll
    for (int dc = 0; dc < 8; ++dc) qf[dc] = *(const bf16x8*)(qp + dc * 32);
  }

  // staging addresses (LDS dest linear per seg; global source pre-swizzled)
  const unsigned char* ksrc[4];
  const unsigned char* vsrc[4];
  unsigned int kofs[4], vofs[4];
#pragma unroll
  for (int ii = 0; ii < 4; ++ii) {
    int seg = w * 4 + ii;
    {
      int r = seg * 4 + (lane >> 4);
      int kcol = ((lane & 15) * 16) ^ ((r & 15) << 4);
      ksrc[ii] = (const unsigned char*)(Kb + (size_t)(kv0 + r) * 128) + kcol;
      kofs[ii] = seg * 1024;
    }
    {
      int o = seg * 1024 + lane * 16;      // linear LDS offset in V region
      int R = o >> 8;
      int cp = (o & 255) ^ ((R & 15) << 4);
      int d = 2 * R + (cp >> 7);
      int kvb = cp & 127;
      vsrc[ii] = (const unsigned char*)(Vb + (size_t)d * 4096 + kv0) + kvb;
      vofs[ii] = 16384 + seg * 1024;
    }
  }

  f32x16 acc[4];
#pragma unroll
  for (int i = 0; i < 4; ++i)
#pragma unroll
    for (int e = 0; e < 16; ++e) acc[i][e] = 0.f;
  float m = -1e30f, l = 0.f;

#pragma unroll
  for (int ii = 0; ii < 4; ++ii) {
    async_copy16(smem + kofs[ii], ksrc[ii]);
    async_copy16(smem + vofs[ii], vsrc[ii]);
  }
  __syncthreads();

#pragma unroll 2
  for (int it = 0; it < 32; ++it) {
    unsigned char* bb = smem + (it & 1) * 32768;
    if (it + 1 < 32) {
      unsigned int nb = ((it + 1) & 1) * 32768;
      size_t ko = (size_t)(it + 1) * 16384;
      int vo2 = (it + 1) * 128;
#pragma unroll
      for (int ii = 0; ii < 4; ++ii) {
        async_copy16(smem + nb + kofs[ii], ksrc[ii] + ko);
        async_copy16(smem + nb + vofs[ii], vsrc[ii] + vo2);
      }
    }

    // S^T = K·Q^T : two 32-kv tiles, 8 d-steps each
    f32x16 st0, st1;
#pragma unroll
    for (int e = 0; e < 16; ++e) { st0[e] = 0.f; st1[e] = 0.f; }
    const unsigned char* kb0 = bb + q31 * 256;
    const unsigned char* kb1 = bb + (32 + q31) * 256;
    __builtin_amdgcn_s_setprio(1);
#pragma unroll
    for (int dc = 0; dc < 8; ++dc) {
      int off = (dc * 32 + hi * 16) ^ kswz;
      bf16x8 k0 = *(const bf16x8*)(kb0 + off);
      bf16x8 k1 = *(const bf16x8*)(kb1 + off);
      st0 = __builtin_amdgcn_mfma_f32_32x32x16_bf16(k0, qf[dc], st0, 0, 0, 0);
      st1 = __builtin_amdgcn_mfma_f32_32x32x16_bf16(k1, qf[dc], st1, 0, 0, 0);
    }
    __builtin_amdgcn_s_setprio(0);

    // gated wave-uniform online max: per-lane tree, then __any gate;
    // 6-shfl wave reduce + rescale only when the threshold fires.
    float t8[8];
#pragma unroll
    for (int e = 0; e < 8; ++e)
      t8[e] = fmaxf(fmaxf(st0[e], st0[e + 8]), fmaxf(st1[e], st1[e + 8]));
#pragma unroll
    for (int e = 0; e < 4; ++e) t8[e] = fmaxf(t8[e], t8[e + 4]);
    float tl = fmaxf(fmaxf(t8[0], t8[1]), fmaxf(t8[2], t8[3]));
    if (__any(tl > m + 8.f)) {  // == (wave_max > m+8); uniform branch
      float tmax = tl;
#pragma unroll
      for (int off = 1; off < 64; off <<= 1)
        tmax = fmaxf(tmax, __shfl_xor(tmax, off));
      float mn = fmaxf(m, tmax);
      float sc = __expf(m - mn);
      m = mn;
      l *= sc;
#pragma unroll
      for (int i = 0; i < 4; ++i)
#pragma unroll
        for (int e = 0; e < 16; ++e) acc[i][e] *= sc;
    }
    float ls = 0.f;
#pragma unroll
    for (int e = 0; e < 16; ++e) { st0[e] = __expf(st0[e] - m); ls += st0[e]; }
#pragma unroll
    for (int e = 0; e < 16; ++e) { st1[e] = __expf(st1[e] - m); ls += st1[e]; }
    l += ls;

    // O += P·V : P A-frag in-register (V kv-columns pre-permuted in proj)
    const unsigned char* vbase = bb + 16384 + (q31 >> 1) * 256;
    const int vhb = (q31 & 1) << 7;
    const int vswz = (q31 >> 1) << 4;
#pragma unroll
    for (int ks = 0; ks < 4; ++ks) {
      union { uint32_t u[4]; bf16x8 v; } pk;
      if (ks == 0) {
        pk.u[0] = cvt_pk_bf16(st0[0], st0[1]);
        pk.u[1] = cvt_pk_bf16(st0[2], st0[3]);
        pk.u[2] = cvt_pk_bf16(st0[4], st0[5]);
        pk.u[3] = cvt_pk_bf16(st0[6], st0[7]);
      } else if (ks == 1) {
        pk.u[0] = cvt_pk_bf16(st0[8], st0[9]);
        pk.u[1] = cvt_pk_bf16(st0[10], st0[11]);
        pk.u[2] = cvt_pk_bf16(st0[12], st0[13]);
        pk.u[3] = cvt_pk_bf16(st0[14], st0[15]);
      } else if (ks == 2) {
        pk.u[0] = cvt_pk_bf16(st1[0], st1[1]);
        pk.u[1] = cvt_pk_bf16(st1[2], st1[3]);
        pk.u[2] = cvt_pk_bf16(st1[4], st1[5]);
        pk.u[3] = cvt_pk_bf16(st1[6], st1[7]);
      } else {
        pk.u[0] = cvt_pk_bf16(st1[8], st1[9]);
        pk.u[1] = cvt_pk_bf16(st1[10], st1[11]);
        pk.u[2] = cvt_pk_bf16(st1[12], st1[13]);
        pk.u[3] = cvt_pk_bf16(st1[14], st1[15]);
      }
      __builtin_amdgcn_s_setprio(1);
#pragma unroll
      for (int dt = 0; dt < 4; ++dt) {
        bf16x8 vf = *(const bf16x8*)(
            vbase + dt * 4096 + ((vhb | (ks * 32 + hi * 16)) ^ vswz));
        acc[dt] = __builtin_amdgcn_mfma_f32_32x32x16_bf16(pk.v, vf, acc[dt], 0, 0, 0);
      }
      __builtin_amdgcn_s_setprio(0);
    }
    __syncthreads();
  }

  // epilogue: store partial O (unnormalized bf16) + m, l
  float lf = l + __shfl_xor(l, 32);
  if (lane < 32) {
    size_t ix = (size_t)h * 32768 + (size_t)b * 4096 + qw + q31;
    Marr[ix] = m;
    Larr[ix] = lf;
  }
  unsigned short* ob = Opart + (size_t)h * 32768 * 128;
#pragma unroll
  for (int dt = 0; dt < 4; ++dt)
#pragma unroll
    for (int r = 0; r < 16; ++r) {
      int qrow = qw + (r & 3) + 8 * (r >> 2) + 4 * hi;
      ob[((size_t)b * 4096 + qrow) * 128 + dt * 32 + q31] =
          f32_to_bf16(acc[dt][r]);
    }
}

// ---------------------------------------------------------------------------
// Kernel D: FUSED combine + z = Wz.y + bz + BN + residual (f32 x).
// ---------------------------------------------------------------------------
__global__ __launch_bounds__(512, 2) void outz_kernel(
    const unsigned short* __restrict__ Opart,
    const float* __restrict__ Marr, const float* __restrict__ Larr,
    const unsigned short* __restrict__ Wzb,
    const float* __restrict__ x, const float* __restrict__ bz,
    const float* __restrict__ gamma, const float* __restrict__ beta,
    const float* __restrict__ rmean, const float* __restrict__ rvar,
    float* __restrict__ out) {
  __shared__ __align__(1024) unsigned short ys[128 * 128];
  const int t = threadIdx.x;
  const int lane = t & 63;
  const int w = t >> 6;
  const int nt = blockIdx.x;
  const int b = blockIdx.y;
  const int n0 = nt * 128;

  unsigned char* lbase = (unsigned char*)ys;
#pragma unroll
  for (int i = 0; i < 4; ++i) {
    int off = (w * 4 + i) * 1024 + lane * 16;
    int n = off >> 8;                       // local q row 0..127
    int cb = (off & 255) ^ ((n & 7) << 4);  // byte col in Y row (16-aligned)
    size_t qidx = (size_t)b * 4096 + n0 + n;
    float m0 = Marr[qidx], m1 = Marr[32768 + qidx];
    float l0 = Larr[qidx], l1 = Larr[32768 + qidx];
    float M = fmaxf(m0, m1);
    float e0 = __expf(m0 - M), e1 = __expf(m1 - M);
    float rd = 1.f / (e0 * l0 + e1 * l1);
    float f0 = e0 * rd, f1 = e1 * rd;
    const unsigned char* ob = (const unsigned char*)Opart;
    const bf16x8 o0 = *(const bf16x8*)(ob + qidx * 256 + cb);
    const bf16x8 o1 = *(const bf16x8*)(ob + 32768ull * 256 + qidx * 256 + cb);
    union { uint4 u4; unsigned short s[8]; } pk;
#pragma unroll
    for (int e = 0; e < 8; ++e)
      pk.s[e] = f32_to_bf16(f0 * bf16_to_f32((unsigned short)o0[e]) +
                            f1 * bf16_to_f32((unsigned short)o1[e]));
    *(uint4*)(lbase + off) = pk.u4;
  }
  __syncthreads();

  const int rl = lane & 15, gh = lane >> 4;
  const int swz = (rl & 7) << 4;

  f32x4 acc[2][8];
#pragma unroll
  for (int i = 0; i < 2; ++i)
#pragma unroll
    for (int j = 0; j < 8; ++j) acc[i][j] = (f32x4){0.f, 0.f, 0.f, 0.f};

  const unsigned char* wz0 =
      (const unsigned char*)Wzb + ((w * 2) * 16 + rl) * 256 + gh * 16;

#pragma unroll
  for (int kk = 0; kk < 4; ++kk) {
    bf16x8 yf[8];
#pragma unroll
    for (int n2 = 0; n2 < 8; ++n2)
      yf[n2] = *(const bf16x8*)(lbase + (n2 * 16 + rl) * 256 +
                                ((kk * 64 + gh * 16) ^ swz));
    bf16x8 f0 = *(const bf16x8*)(wz0 + kk * 64);
    bf16x8 f1 = *(const bf16x8*)(wz0 + 16 * 256 + kk * 64);
#pragma unroll
    for (int n2 = 0; n2 < 8; ++n2) {
      acc[0][n2] = __builtin_amdgcn_mfma_f32_16x16x32_bf16(f0, yf[n2], acc[0][n2], 0, 0, 0);
      acc[1][n2] = __builtin_amdgcn_mfma_f32_16x16x32_bf16(f1, yf[n2], acc[1][n2], 0, 0, 0);
    }
  }

#pragma unroll
  for (int ot = 0; ot < 2; ++ot) {
#pragma unroll
    for (int j = 0; j < 4; ++j) {
      int o = (w * 2 + ot) * 16 + gh * 4 + j;
      float scale = gamma[o] * rsqrtf(rvar[o] + 1e-5f);
      float shift = (bz[o] - rmean[o]) * scale + beta[o];
      const float* xr = x + ((size_t)b * 256 + o) * 4096 + n0;
      float* orow = out + ((size_t)b * 256 + o) * 4096 + n0;
#pragma unroll
      for (int n2 = 0; n2 < 8; ++n2) {
        int n = n2 * 16 + rl;
        orow[n] = acc[ot][n2][j] * scale + shift + xr[n];
      }
    }
  }
}

// ---------------------------------------------------------------------------
extern "C" void kernel_launch(void* const* d_in, const int* in_sizes, int n_in,
                              void* d_out, int out_size, void* d_ws,
                              size_t ws_size, hipStream_t stream) {
  const float* x     = (const float*)d_in[0];
  const float* Wt    = (const float*)d_in[1];
  const float* bt    = (const float*)d_in[2];
  const float* Wp    = (const float*)d_in[3];
  const float* bp    = (const float*)d_in[4];
  const float* Wg    = (const float*)d_in[5];
  const float* bg    = (const float*)d_in[6];
  const float* Wz    = (const float*)d_in[7];
  const float* bz    = (const float*)d_in[8];
  const float* gamma = (const float*)d_in[9];
  const float* beta  = (const float*)d_in[10];
  const float* rmean = (const float*)d_in[11];
  const float* rvar  = (const float*)d_in[12];
  float* out = (float*)d_out;

  const size_t NE = (size_t)8 * 4096 * 128;  // 4,194,304
  unsigned short* Wcat  = (unsigned short*)d_ws;       // 98304 sh
  unsigned short* Wzb   = Wcat + 98304;                // 32768 sh
  float*          Marr  = (float*)(Wzb + 32768);       // 2*32768 f32
  float*          Larr  = Marr + 2 * 32768;            // 2*32768 f32
  unsigned short* Opart = (unsigned short*)(Larr + 2 * 32768);  // 2*NE sh
  unsigned short* Q     = Opart + 2 * NE;
  unsigned short* Km    = Q + NE;
  unsigned short* Vt    = Km + NE;

  wcvt_kernel<<<128, 256, 0, stream>>>(Wt, Wp, Wg, Wz, Wcat, Wzb);
  proj_kernel<<<dim3(32, 8), 512, 0, stream>>>(x, Wcat, bt, bp, bg, Q, Km, Vt);
  attn_kernel<<<512, 256, 0, stream>>>(Q, Km, Vt, Opart, Marr, Larr);
  outz_kernel<<<dim3(32, 8), 512, 0, stream>>>(Opart, Marr, Larr, Wzb, x, bz,
                                               gamma, beta, rmean, rvar, out);
}